// Round 15
// baseline (187.151 us; speedup 1.0000x reference)
//
#include <hip/hip_runtime.h>
#include <cstdint>

#define BLOCK_SIZE 256
#define NPOS 63   // 9*7 spatial positions per batch

typedef __attribute__((ext_vector_type(8))) short bf16x8;       // 8 bf16, 4 VGPRs
typedef __attribute__((ext_vector_type(4))) float f32x4;
typedef __attribute__((ext_vector_type(4))) unsigned int uint4v;

// pack hi16(ha):hi16(hb) -> one dword in ONE v_perm_b32 (short0=ha, short1=hb)
__device__ __forceinline__ unsigned pack_hi16(float ha, float hb) {
    return __builtin_amdgcn_perm(__float_as_uint(hb), __float_as_uint(ha), 0x07060302u);
}
__device__ __forceinline__ float lo_part(float h) {
    return h - __uint_as_float(__float_as_uint(h) & 0xFFFF0000u);
}
// round-to-nearest-even bf16 bits (returned in low 16)
__device__ __forceinline__ unsigned rne_bf16(float a) {
    const unsigned u = __float_as_uint(a);
    return (u + 0x7FFFu + ((u >> 16) & 1u)) >> 16;
}

// R14 -> R15: occupancy via live-range surgery. R14 held 48 VGPRs of
// epilogue-only W3 constants across the whole kernel (VGPR=80 => 6
// waves/SIMD, latency-bound at VALUBusy 65%). Now W3 views are re-loaded
// per i-tile from global (L1-resident, 8x16B) with an asm-opaqued offset so
// LICM cannot hoist them back. Target VGPR <=64 => 8 waves/SIMD.
// All numerics identical to R14 (2-product split: W2 RNE bf16, h1 Dekker).
__global__ __launch_bounds__(BLOCK_SIZE) void carnet_fused(
    const float* __restrict__ x,      // (B, 9, 7) flat
    const int*   __restrict__ adj,    // (B, 45)
    const float* __restrict__ ctx,    // (B, 45)
    const float* __restrict__ gcn_W,  // (7, 7)
    const float* __restrict__ gcn_b,  // (7)
    const float* __restrict__ ctx_W,  // (45, 63)
    const float* __restrict__ ctx_b,  // (63)
    const float* __restrict__ W1,     // (64, 2)
    const float* __restrict__ b1,     // (64)
    const float* __restrict__ W2,     // (64, 64)
    const float* __restrict__ b2,     // (64)
    const float* __restrict__ W3,     // (2, 64)
    const float* __restrict__ b3,     // (2)
    float* __restrict__ out)          // (B, 2, 9, 7) flat
{
    __shared__ short sh2b[64 * 64];   // 8192 B, XOR-swizzled, RNE bf16 of W2

    const int t    = threadIdx.x;
    const int lane = t & 63;

    // ---- staging: W2 fp32 -> RNE bf16 plane, swizzled LDS write ----
    {
        const int r  = t >> 2;
        const int cq = t & 3;
        const float* wsrc = W2 + r * 64 + cq * 16;
        const float4 w0 = ((const float4*)wsrc)[0];
        const float4 w1 = ((const float4*)wsrc)[1];
        const float4 w2v = ((const float4*)wsrc)[2];
        const float4 w3v = ((const float4*)wsrc)[3];
        uint4v hA = { rne_bf16(w0.x)  | (rne_bf16(w0.y)  << 16),
                      rne_bf16(w0.z)  | (rne_bf16(w0.w)  << 16),
                      rne_bf16(w1.x)  | (rne_bf16(w1.y)  << 16),
                      rne_bf16(w1.z)  | (rne_bf16(w1.w)  << 16) };
        uint4v hB = { rne_bf16(w2v.x) | (rne_bf16(w2v.y) << 16),
                      rne_bf16(w2v.z) | (rne_bf16(w2v.w) << 16),
                      rne_bf16(w3v.x) | (rne_bf16(w3v.y) << 16),
                      rne_bf16(w3v.z) | (rne_bf16(w3v.w) << 16) };
        const int sA = ((2 * cq)     ^ (r & 7)) * 8;
        const int sB = ((2 * cq + 1) ^ (r & 7)) * 8;
        *(uint4v*)&sh2b[r * 64 + sA] = hA;
        *(uint4v*)&sh2b[r * 64 + sB] = hB;
    }

    // ================= PHASE 1: z, c (R10-proven, wave = batch) ==========
    const int b = __builtin_amdgcn_readfirstlane(blockIdx.x * 4 + (t >> 6));
    const int p = lane < 63 ? lane : 62;
    const int n = p / 7;
    const int f = p - n * 7;

    const int* ab = adj + b * 45;
    uint64_t am = 0;
#pragma unroll
    for (int i = 0; i < 45; ++i)
        am |= (uint64_t)(ab[i] != 0) << i;

    float d[9];
#pragma unroll
    for (int i = 0; i < 9; ++i) {
        const int s = 9 * i - (i * (i - 1)) / 2;
        const int w = 8 - i;
        const uint64_t bits = (am >> (s + 1)) & ((1ull << w) - 1ull);
        d[i] = __frsqrt_rn((float)(1 + __popcll(bits)));
    }

    const float* xb = x + b * 63;
    float yv = 0.f;
#pragma unroll
    for (int k = 0; k < 7; ++k)
        yv = fmaf(xb[n * 7 + k], gcn_W[k * 7 + f], yv);

    float zt = 0.f;
    const int snn = 9 * n - (n * (n - 1)) / 2 - n;
#pragma unroll
    for (int m = 0; m < 9; ++m) {
        const float ym = __shfl(yv, m * 7 + f);
        int sh = snn + m;
        sh = sh < 0 ? 0 : sh;
        const bool conn = (m == n) || ((m > n) && ((am >> sh) & 1ull));
        zt = fmaf(conn ? d[m] : 0.f, ym, zt);
    }
    const float zv = fmaf(d[n], zt, gcn_b[f]);

    // ctx dot with 4 accumulators (shorter dependency chain)
    const float* cb = ctx + b * 45;
    float ca0 = ctx_b[p], ca1 = 0.f, ca2 = 0.f, ca3 = 0.f;
#pragma unroll
    for (int q = 0; q < 44; q += 4) {
        ca0 = fmaf(cb[q],     ctx_W[q * 63 + p],       ca0);
        ca1 = fmaf(cb[q + 1], ctx_W[(q + 1) * 63 + p], ca1);
        ca2 = fmaf(cb[q + 2], ctx_W[(q + 2) * 63 + p], ca2);
        ca3 = fmaf(cb[q + 3], ctx_W[(q + 3) * 63 + p], ca3);
    }
    ca0 = fmaf(cb[44], ctx_W[44 * 63 + p], ca0);
    const float cvv = fmaxf((ca0 + ca1) + (ca2 + ca3), 0.f);

    // ================= PHASE 2: MFMA (operand-swapped, 2-product) =======
    const int cl   = lane & 15;       // position within i-tile (B-operand n)
    const int quad = lane >> 4;       // k-octet / C row group (channel)
    const int s0 = (quad ^ (cl & 7)) * 16;

    float2 wp0[8], wp1[8];
    float  bb0[8], bb1[8];
#pragma unroll
    for (int j = 0; j < 8; ++j) {
        const int o = quad * 8 + j;
        wp0[j] = *(const float2*)(W1 + 2 * o);
        bb0[j] = b1[o];
        wp1[j] = *(const float2*)(W1 + 2 * (o + 32));
        bb1[j] = b1[o + 32];
    }

    // b2 views stay resident (needed BEFORE the MFMAs each tile).
    const float4 b2q0 = *(const float4*)(b2 + quad * 4);
    const float4 b2q1 = *(const float4*)(b2 + 16 + quad * 4);
    const float4 b2q2 = *(const float4*)(b2 + 32 + quad * 4);
    const float4 b2q3 = *(const float4*)(b2 + 48 + quad * 4);
    const float b30 = b3[0], b31 = b3[1];
    float* __restrict__ ob = out + b * 126;

    const char* sh2bB = (const char*)sh2b;
    const char* w3B   = (const char*)W3;

    __syncthreads();   // staging complete before first B read

#pragma unroll 1
    for (int i = 0; i < 4; ++i) {
        const float zm = __shfl(zv,  i * 16 + cl);
        const float cm = __shfl(cvv, i * 16 + cl);

        // h1 fragments (MFMA B operand): exact Dekker hi/lo split.
        uint4v ph0, pl0, ph1, pl1;
#pragma unroll
        for (int jj = 0; jj < 4; ++jj) {
            float ha = fmaxf(fmaf(wp0[2*jj].x,   zm, fmaf(wp0[2*jj].y,   cm, bb0[2*jj])),   0.f);
            float hb = fmaxf(fmaf(wp0[2*jj+1].x, zm, fmaf(wp0[2*jj+1].y, cm, bb0[2*jj+1])), 0.f);
            ph0[jj] = pack_hi16(ha, hb);
            pl0[jj] = pack_hi16(lo_part(ha), lo_part(hb));

            ha = fmaxf(fmaf(wp1[2*jj].x,   zm, fmaf(wp1[2*jj].y,   cm, bb1[2*jj])),   0.f);
            hb = fmaxf(fmaf(wp1[2*jj+1].x, zm, fmaf(wp1[2*jj+1].y, cm, bb1[2*jj+1])), 0.f);
            ph1[jj] = pack_hi16(ha, hb);
            pl1[jj] = pack_hi16(lo_part(ha), lo_part(hb));
        }
        const bf16x8 ah0 = __builtin_bit_cast(bf16x8, ph0);
        const bf16x8 al0 = __builtin_bit_cast(bf16x8, pl0);
        const bf16x8 ah1 = __builtin_bit_cast(bf16x8, ph1);
        const bf16x8 al1 = __builtin_bit_cast(bf16x8, pl1);

        f32x4 acc0 = {b2q0.x, b2q0.y, b2q0.z, b2q0.w};
        f32x4 acc1 = {b2q1.x, b2q1.y, b2q1.z, b2q1.w};
        f32x4 acc2 = {b2q2.x, b2q2.y, b2q2.z, b2q2.w};
        f32x4 acc3 = {b2q3.x, b2q3.y, b2q3.z, b2q3.w};

        // A = W2 bf16 frag (LDS, 2 reads/STEP), B = h1 hi/lo (4 MFMAs/STEP).
#define STEP(nt) {                                                                    \
        int bo = cl * 128 + s0;                                                       \
        asm volatile("" : "+v"(bo));                                                  \
        const int bo2 = (cl * 128) | (s0 ^ 64);                                       \
        const bf16x8 wf0 = *(const bf16x8*)(sh2bB + bo  + ((nt) * 2048));             \
        const bf16x8 wf1 = *(const bf16x8*)(sh2bB + bo2 + ((nt) * 2048));             \
        acc##nt = __builtin_amdgcn_mfma_f32_16x16x32_bf16(wf0, ah0, acc##nt, 0, 0, 0); \
        acc##nt = __builtin_amdgcn_mfma_f32_16x16x32_bf16(wf0, al0, acc##nt, 0, 0, 0); \
        acc##nt = __builtin_amdgcn_mfma_f32_16x16x32_bf16(wf1, ah1, acc##nt, 0, 0, 0); \
        acc##nt = __builtin_amdgcn_mfma_f32_16x16x32_bf16(wf1, al1, acc##nt, 0, 0, 0); }
        STEP(0) STEP(1) STEP(2) STEP(3)
#undef STEP

        // Epilogue: W3 views re-loaded HERE per tile (asm-opaqued offset =>
        // no LICM hoist => not resident across the kernel). 8x16B, L1-hit
        // after tile 0; the 16 MFMAs above are the latency cover.
        int w3off = quad * 16;
        asm volatile("" : "+v"(w3off));
        const float4 wa0 = *(const float4*)(w3B + w3off);
        const float4 wa1 = *(const float4*)(w3B + 64 + w3off);
        const float4 wa2 = *(const float4*)(w3B + 128 + w3off);
        const float4 wa3 = *(const float4*)(w3B + 192 + w3off);
        const float4 wb0 = *(const float4*)(w3B + 256 + w3off);
        const float4 wb1 = *(const float4*)(w3B + 320 + w3off);
        const float4 wb2 = *(const float4*)(w3B + 384 + w3off);
        const float4 wb3 = *(const float4*)(w3B + 448 + w3off);

        float q0, q1;
        {
            float h;
            h = fmaxf(acc0[0], 0.f); q0 = h * wa0.x;            q1 = h * wb0.x;
            h = fmaxf(acc0[1], 0.f); q0 = fmaf(h, wa0.y, q0);   q1 = fmaf(h, wb0.y, q1);
            h = fmaxf(acc0[2], 0.f); q0 = fmaf(h, wa0.z, q0);   q1 = fmaf(h, wb0.z, q1);
            h = fmaxf(acc0[3], 0.f); q0 = fmaf(h, wa0.w, q0);   q1 = fmaf(h, wb0.w, q1);
            h = fmaxf(acc1[0], 0.f); q0 = fmaf(h, wa1.x, q0);   q1 = fmaf(h, wb1.x, q1);
            h = fmaxf(acc1[1], 0.f); q0 = fmaf(h, wa1.y, q0);   q1 = fmaf(h, wb1.y, q1);
            h = fmaxf(acc1[2], 0.f); q0 = fmaf(h, wa1.z, q0);   q1 = fmaf(h, wb1.z, q1);
            h = fmaxf(acc1[3], 0.f); q0 = fmaf(h, wa1.w, q0);   q1 = fmaf(h, wb1.w, q1);
            h = fmaxf(acc2[0], 0.f); q0 = fmaf(h, wa2.x, q0);   q1 = fmaf(h, wb2.x, q1);
            h = fmaxf(acc2[1], 0.f); q0 = fmaf(h, wa2.y, q0);   q1 = fmaf(h, wb2.y, q1);
            h = fmaxf(acc2[2], 0.f); q0 = fmaf(h, wa2.z, q0);   q1 = fmaf(h, wb2.z, q1);
            h = fmaxf(acc2[3], 0.f); q0 = fmaf(h, wa2.w, q0);   q1 = fmaf(h, wb2.w, q1);
            h = fmaxf(acc3[0], 0.f); q0 = fmaf(h, wa3.x, q0);   q1 = fmaf(h, wb3.x, q1);
            h = fmaxf(acc3[1], 0.f); q0 = fmaf(h, wa3.y, q0);   q1 = fmaf(h, wb3.y, q1);
            h = fmaxf(acc3[2], 0.f); q0 = fmaf(h, wa3.z, q0);   q1 = fmaf(h, wb3.z, q1);
            h = fmaxf(acc3[3], 0.f); q0 = fmaf(h, wa3.w, q0);   q1 = fmaf(h, wb3.w, q1);
        }
        q0 += __shfl_xor(q0, 16); q0 += __shfl_xor(q0, 32);
        q1 += __shfl_xor(q1, 16); q1 += __shfl_xor(q1, 32);

        const int pp = i * 16 + cl;
        if (quad == 0 && pp < NPOS) {
            ob[pp]        = q0 + b30;
            ob[NPOS + pp] = q1 + b31;
        }
    }
}

extern "C" void kernel_launch(void* const* d_in, const int* in_sizes, int n_in,
                              void* d_out, int out_size, void* d_ws, size_t ws_size,
                              hipStream_t stream) {
    const float* x     = (const float*)d_in[0];
    const int*   adj   = (const int*)  d_in[1];
    const float* ctx   = (const float*)d_in[2];
    const float* gcn_W = (const float*)d_in[3];
    const float* gcn_b = (const float*)d_in[4];
    const float* ctx_W = (const float*)d_in[5];
    const float* ctx_b = (const float*)d_in[6];
    const float* W1    = (const float*)d_in[7];
    const float* b1    = (const float*)d_in[8];
    const float* W2    = (const float*)d_in[9];
    const float* b2    = (const float*)d_in[10];
    const float* W3    = (const float*)d_in[11];
    const float* b3    = (const float*)d_in[12];
    float* out = (float*)d_out;

    const int nbatch = in_sizes[1] / 45;            // B = 32768
    const int grid = (nbatch + 3) / 4;              // 4 batches (waves) per block
    carnet_fused<<<grid, BLOCK_SIZE, 0, stream>>>(
        x, adj, ctx, gcn_W, gcn_b, ctx_W, ctx_b,
        W1, b1, W2, b2, W3, b3, out);
}